// Round 4
// baseline (291.586 us; speedup 1.0000x reference)
//
#include <hip/hip_runtime.h>

// out[b,s] = cumsum_s( softplus(beta * c[b,s]) / beta ), fp32, B=4096, S=8192.
//
// R5 design: LANE-LOCAL SCAN. One wave per row; lane owns CONTIGUOUS elems.
//   Post-mortem R2-R4: three different structures all ~84us, every pipe <35%
//   busy. The invariant: 6-step DEPENDENT __shfl_up chains (ds_bpermute,
//   ~120cyc latency each) -- R4 ran 192 bpermutes/wave in 8 serial passes
//   the compiler couldn't overlap. The scan *topology* was the stall.
//   Fix: map the serial dimension INTO the lane.
//   - Row (8192) = 4 segments x 2048. Lane l owns elems [seg*2048+l*32, +32)
//     = 8 contiguous float4. In-lane inclusive scan = 32 dependent v_adds
//     (~4cyc each, fully hidden). Cross-lane per segment: ONE 6-step wave
//     scan of lane totals + 1 broadcast -> 28 cross-lane ops/row vs 192.
//   - Coalescing: per-lane-contiguous loads at 128B lane stride touch the
//     same 2 lines per lane for 4 consecutive k -> L1 absorbs; amortized
//     16 lines/instr == coalesced rate. Stores merge in L2 (back-to-back
//     partials). FETCH/WRITE_SIZE counters verify both claims.
//   - Ping-pong va/vb: segment s+2 loads issued right after s is consumed;
//     no barrier, no LDS, loads stay outstanding continuously.
//   - 4096 waves (1024 blocks x 256 thr), 16 waves/CU, ~96-112 VGPR.

#define ROW_S    8192
#define NSEG     4
#define SEG_ELEM (ROW_S / NSEG)          // 2048 elems per segment
#define LANE_F4  8                       // float4 per lane per segment (32 elems)
#define SEG_F4   (SEG_ELEM / 4)          // 512 float4 per segment
#define WPB      4
#define BLOCK_T  (WPB * 64)

typedef float f32x4 __attribute__((ext_vector_type(4)));

__device__ __forceinline__ float softplus_step(float c, float beta, float inv_beta) {
    float tb = beta * c;
    float a  = fabsf(tb);
    float e  = __expf(-a);             // in (0,1], no overflow
    float l  = __logf(1.0f + e);       // log1p(exp(-|t|))
    return (fmaxf(tb, 0.0f) + l) * inv_beta;
}

__global__ __launch_bounds__(BLOCK_T, 4) void softplus_cumsum_kernel(
    const float* __restrict__ c,
    const float* __restrict__ beta_p,
    float* __restrict__ out,
    int nrows)
{
    const int lane = threadIdx.x & 63;
    const int wave = threadIdx.x >> 6;
    const int row  = blockIdx.x * WPB + wave;
    if (row >= nrows) return;                       // wave-uniform exit

    const float beta     = beta_p[0];
    const float inv_beta = 1.0f / beta;

    const f32x4* __restrict__ in4  = (const f32x4*)c   + (size_t)row * (ROW_S / 4);
    f32x4*       __restrict__ out4 = (f32x4*)out       + (size_t)row * (ROW_S / 4);
    const int lb = lane * LANE_F4;                  // lane's float4 base in a segment

    float carry = 0.0f;

    // ---- 2-deep pipeline prologue: segments 0 and 1 in flight ----
    f32x4 va[LANE_F4], vb[LANE_F4];
    #pragma unroll
    for (int k = 0; k < LANE_F4; ++k) va[k] = in4[0 * SEG_F4 + lb + k];
    #pragma unroll
    for (int k = 0; k < LANE_F4; ++k) vb[k] = in4[1 * SEG_F4 + lb + k];

    // body(cur, s): consume segment s from cur, refill cur with segment s+2.
    auto body = [&](f32x4 (&cur)[LANE_F4], const int s) {
        // softplus + IN-LANE inclusive scan (serial per lane, zero cross-lane)
        f32x4 r[LANE_F4];
        float acc = 0.0f;
        #pragma unroll
        for (int k = 0; k < LANE_F4; ++k) {
            acc += softplus_step(cur[k].x, beta, inv_beta);  r[k].x = acc;
            acc += softplus_step(cur[k].y, beta, inv_beta);  r[k].y = acc;
            acc += softplus_step(cur[k].z, beta, inv_beta);  r[k].z = acc;
            acc += softplus_step(cur[k].w, beta, inv_beta);  r[k].w = acc;
        }
        const float total = acc;

        // refill: issue loads for segment s+2 into the freed buffer
        if (s + 2 < NSEG) {
            #pragma unroll
            for (int k = 0; k < LANE_F4; ++k)
                cur[k] = in4[(s + 2) * SEG_F4 + lb + k];
        }

        // ONE wave-inclusive shuffle scan of the 64 lane totals
        float x = total;
        #pragma unroll
        for (int d = 1; d < 64; d <<= 1) {
            float y = __shfl_up(x, d, 64);
            if (lane >= d) x += y;
        }
        const float off    = carry + (x - total);   // exclusive lane prefix
        const float segtot = __shfl(x, 63, 64);     // segment total (broadcast)
        carry += segtot;

        // stores: per-lane contiguous, L2 merges back-to-back partial lines
        #pragma unroll
        for (int k = 0; k < LANE_F4; ++k) {
            f32x4 o;
            o.x = r[k].x + off;
            o.y = r[k].y + off;
            o.z = r[k].z + off;
            o.w = r[k].w + off;
            out4[s * SEG_F4 + lb + k] = o;
        }
    };

    // NSEG = 4, fully static ping-pong (no runtime-indexed buffers -> no scratch)
    body(va, 0); body(vb, 1);
    body(va, 2); body(vb, 3);
}

extern "C" void kernel_launch(void* const* d_in, const int* in_sizes, int n_in,
                              void* d_out, int out_size, void* d_ws, size_t ws_size,
                              hipStream_t stream) {
    const float* c      = (const float*)d_in[0];
    const float* beta_p = (const float*)d_in[1];
    float*       out    = (float*)d_out;

    const int B    = in_sizes[0] / ROW_S;            // 4096 rows
    const int grid = (B + WPB - 1) / WPB;            // 1024 blocks

    softplus_cumsum_kernel<<<dim3(grid), dim3(BLOCK_T), 0, stream>>>(
        c, beta_p, out, B);
}

// Round 5
// 239.855 us; speedup vs baseline: 1.2157x; 1.2157x over previous
//
#include <hip/hip_runtime.h>

// out[b,s] = cumsum_s( softplus(beta * c[b,s]) / beta ), fp32, B=4096, S=8192.
//
// R6 design: R4 skeleton + FORCED deep pipeline.
//   Post-mortem R4/R2: VGPR_Count=32 proves the compiler SANK the "prefetch"
//   loads to their use sites (2 buffers + scan regs can't fit in 32 VGPRs).
//   No pipeline ever existed: every pass paid full loaded-latency serially.
//   R5: lane-contiguous stores RMW-amplified (WRITE 131->240GB); layout
//   reverted to coalesced f4.
//   Fix here:
//   - 3 static pass-buffers X,Y,Z (NJ=4 f4 each). Body p consumes buffer
//     p%3 and refills it with pass p+3 -> 2 passes (8KB/wave) of loads
//     always in flight, never drained (no barriers anywhere).
//   - asm volatile("" ::: "memory") fences after the prologue and after
//     each refill: compiler memory barrier -> loads cannot sink past it.
//   - __launch_bounds__(256,4): VGPR cap 128 (expect ~90-110 used).
//     VGPR_Count in the profile is the diagnostic: ~32 means fences failed.
//   - One wave per row, 4096 waves (1024 blocks x 256), coalesced f4
//     loads/stores, scan = in-f4 + 4 independent 6-step wave shuffle scans
//     per pass + scalar carry.

#define ROW_S   8192
#define NJ      4                        // float4 chunks per lane per pass
#define PASS_F4 (64 * NJ)                // 256 float4 = 1024 elems per pass
#define NPASS   (ROW_S / (PASS_F4 * 4))  // 8 passes per row
#define WPB     4                        // waves per block
#define BLOCK_T (WPB * 64)

typedef float f32x4 __attribute__((ext_vector_type(4)));

__device__ __forceinline__ float softplus_step(float c, float beta, float inv_beta) {
    float tb = beta * c;
    float a  = fabsf(tb);
    float e  = __expf(-a);             // in (0,1], no overflow
    float l  = __logf(1.0f + e);       // log1p(exp(-|t|))
    return (fmaxf(tb, 0.0f) + l) * inv_beta;
}

__global__ __launch_bounds__(BLOCK_T, 4) void softplus_cumsum_kernel(
    const float* __restrict__ c,
    const float* __restrict__ beta_p,
    float* __restrict__ out,
    int nrows)
{
    const int lane = threadIdx.x & 63;
    const int wave = threadIdx.x >> 6;
    const int row  = blockIdx.x * WPB + wave;
    if (row >= nrows) return;                       // wave-uniform exit

    const float beta     = beta_p[0];
    const float inv_beta = 1.0f / beta;

    const f32x4* __restrict__ in4  = (const f32x4*)c   + (size_t)row * (ROW_S / 4);
    f32x4*       __restrict__ out4 = (f32x4*)out       + (size_t)row * (ROW_S / 4);

    // ---- 3-deep prologue: passes 0,1,2 in flight (12 loads, 12KB) ----
    f32x4 X[NJ], Y[NJ], Z[NJ];
    #pragma unroll
    for (int j = 0; j < NJ; ++j) X[j] = in4[0 * PASS_F4 + j * 64 + lane];
    #pragma unroll
    for (int j = 0; j < NJ; ++j) Y[j] = in4[1 * PASS_F4 + j * 64 + lane];
    #pragma unroll
    for (int j = 0; j < NJ; ++j) Z[j] = in4[2 * PASS_F4 + j * 64 + lane];
    asm volatile("" ::: "memory");   // pin: prologue loads issued HERE

    float carry = 0.0f;

    // Body: consume CUR (= pass P), refill CUR with pass P+3, scan, store.
    // Fences stop the refill loads from sinking below the scan/stores.
#define BODY(CUR, P)                                                          \
    {                                                                         \
        f32x4 r[NJ]; float s[NJ];                                             \
        _Pragma("unroll")                                                     \
        for (int j = 0; j < NJ; ++j) {                                        \
            float a = softplus_step(CUR[j].x, beta, inv_beta);                \
            float b = softplus_step(CUR[j].y, beta, inv_beta);                \
            float d = softplus_step(CUR[j].z, beta, inv_beta);                \
            float e = softplus_step(CUR[j].w, beta, inv_beta);                \
            r[j].x = a;                                                       \
            r[j].y = a + b;                                                   \
            r[j].z = r[j].y + d;                                              \
            r[j].w = r[j].z + e;                                              \
            s[j]   = r[j].w;                                                  \
        }                                                                     \
        if ((P) + 3 < NPASS) {                                                \
            _Pragma("unroll")                                                 \
            for (int j = 0; j < NJ; ++j)                                      \
                CUR[j] = in4[((P) + 3) * PASS_F4 + j * 64 + lane];            \
        }                                                                     \
        asm volatile("" ::: "memory");  /* refill issued before scan/store */ \
        float xs[NJ], G[NJ];                                                  \
        _Pragma("unroll")                                                     \
        for (int j = 0; j < NJ; ++j) {                                        \
            float x = s[j];                                                   \
            _Pragma("unroll")                                                 \
            for (int d = 1; d < 64; d <<= 1) {                                \
                float y = __shfl_up(x, d, 64);                                \
                if (lane >= d) x += y;                                        \
            }                                                                 \
            xs[j] = x;                                                        \
            G[j]  = __shfl(x, 63, 64);                                        \
        }                                                                     \
        float pre = carry;                                                    \
        _Pragma("unroll")                                                     \
        for (int j = 0; j < NJ; ++j) {                                        \
            const float off = pre + (xs[j] - s[j]);                           \
            pre += G[j];                                                      \
            f32x4 o;                                                          \
            o.x = r[j].x + off;                                               \
            o.y = r[j].y + off;                                               \
            o.z = r[j].z + off;                                               \
            o.w = r[j].w + off;                                               \
            out4[(P) * PASS_F4 + j * 64 + lane] = o;                          \
        }                                                                     \
        carry = pre;                                                          \
        asm volatile("" ::: "memory");  /* stores issued before next body */  \
    }

    BODY(X, 0); BODY(Y, 1); BODY(Z, 2);
    BODY(X, 3); BODY(Y, 4); BODY(Z, 5);
    BODY(X, 6); BODY(Y, 7);
#undef BODY
}

extern "C" void kernel_launch(void* const* d_in, const int* in_sizes, int n_in,
                              void* d_out, int out_size, void* d_ws, size_t ws_size,
                              hipStream_t stream) {
    const float* c      = (const float*)d_in[0];
    const float* beta_p = (const float*)d_in[1];
    float*       out    = (float*)d_out;

    const int B    = in_sizes[0] / ROW_S;            // 4096 rows
    const int grid = (B + WPB - 1) / WPB;            // 1024 blocks

    softplus_cumsum_kernel<<<dim3(grid), dim3(BLOCK_T), 0, stream>>>(
        c, beta_p, out, B);
}